// Round 3
// baseline (15895.958 us; speedup 1.0000x reference)
//
#include <hip/hip_runtime.h>
#include <hip/hip_cooperative_groups.h>
#include <stdint.h>
#include <stddef.h>

namespace cg = cooperative_groups;

// ---------------- problem constants ----------------
#define B_   64
#define L_   512
#define E_   512
#define HL_  1024
#define HS_  256
#define NC_  5
#define KL_  1536
#define KS_  768
#define NWG_L 128
#define NWG_  160

typedef __attribute__((ext_vector_type(8))) short bf16x8;
typedef __attribute__((ext_vector_type(4))) float f32x4;

__device__ __forceinline__ uint16_t f2bf(float f) {
  union { float f; uint32_t u; } v; v.f = f;
  uint32_t r = v.u + 0x7FFFu + ((v.u >> 16) & 1u);
  return (uint16_t)(r >> 16);
}
__device__ __forceinline__ float bf2f(uint16_t h) {
  union { uint32_t u; float f; } v; v.u = ((uint32_t)h) << 16; return v.f;
}
__device__ __forceinline__ float sigm(float x) { return 1.0f / (1.0f + expf(-x)); }

// ---------------- setup kernels ----------------

__global__ __launch_bounds__(256) void k_convw(
    const float* __restrict__ Wihl, const float* __restrict__ Whhl,
    const float* __restrict__ Wihs, const float* __restrict__ Whhs,
    uint16_t* __restrict__ Wl_hi, uint16_t* __restrict__ Wl_lo,
    uint16_t* __restrict__ Ws_hi, uint16_t* __restrict__ Ws_lo) {
  const int N1 = 4096 * KL_;
  const int N2 = 1024 * KS_;
  int idx = blockIdx.x * 256 + threadIdx.x;
  if (idx < N1) {
    int row = idx / KL_, k = idx - row * KL_;
    float v = (k < E_) ? Wihl[row * E_ + k] : Whhl[row * HL_ + (k - E_)];
    uint16_t hi = f2bf(v);
    Wl_hi[idx] = hi;
    Wl_lo[idx] = f2bf(v - bf2f(hi));
  } else if (idx < N1 + N2) {
    int j = idx - N1;
    int row = j / KS_, k = j - row * KS_;
    float v = (k < E_) ? Wihs[row * E_ + k] : Whhs[row * HS_ + (k - E_)];
    uint16_t hi = f2bf(v);
    Ws_hi[j] = hi;
    Ws_lo[j] = f2bf(v - bf2f(hi));
  }
}

__global__ __launch_bounds__(256) void k_embed(
    const int* __restrict__ x, const float* __restrict__ emb,
    uint16_t* __restrict__ Ahi) {
  int idx = blockIdx.x * 256 + threadIdx.x;       // [t][b][k]
  int t = idx >> 15;
  int rem = idx & 32767;
  int b = rem >> 9;
  int k = rem & 511;
  int tok = x[b * L_ + t];
  Ahi[idx] = f2bf(emb[(size_t)tok * E_ + k]);
}

__global__ __launch_bounds__(256) void k_zero(uint32_t* __restrict__ p, int nwords) {
  int idx = blockIdx.x * 256 + threadIdx.x;
  if (idx < nwords) p[idx] = 0u;
}

__global__ __launch_bounds__(256) void k_rseq(
    const float* __restrict__ gum, float* __restrict__ rseq) {
  int idx = blockIdx.x * 256 + threadIdx.x;       // t*64+b
  int t = idx >> 6, b = idx & 63;
  float u0 = gum[(b * L_ + t) * 2 + 0];
  float u1 = gum[(b * L_ + t) * 2 + 1];
  float g0 = -logf(-logf(u0));
  float g1 = -logf(-logf(u1));
  float m = fmaxf(g0, g1);
  float e0 = expf(g0 - m), e1 = expf(g1 - m);
  float inv = 1.0f / (e0 + e1);
  rseq[idx * 2 + 0] = e0 * inv;
  rseq[idx * 2 + 1] = e1 * inv;
}

__global__ __launch_bounds__(256) void k_pe(
    const int* __restrict__ x, const float* __restrict__ emb,
    const float* __restrict__ Wp, float* __restrict__ Pe) {
  int idx = blockIdx.x * 256 + threadIdx.x;       // t*64+b
  int t = idx >> 6, b = idx & 63;
  int tok = x[b * L_ + t];
  const float* row = emb + (size_t)tok * E_;
  float a0 = 0.f, a1 = 0.f;
  for (int k = 0; k < E_; ++k) {
    float e = row[k];
    a0 += e * Wp[k];
    a1 += e * Wp[2560 + k];
  }
  Pe[idx * 2 + 0] = a0;
  Pe[idx * 2 + 1] = a1;
}

// ---------------- persistent scan kernel ----------------
struct ScanArgs {
  const uint16_t* Ahi;
  const uint16_t* Wl_hi; const uint16_t* Wl_lo;
  const uint16_t* Ws_hi; const uint16_t* Ws_lo;
  uint16_t* h_hi; uint16_t* h_lo;
  uint16_t* hs_hi; uint16_t* hs_lo;
  float* hs_f32; float* cs_f32;
  const float* rseq;
  const float* bihl; const float* bhhl;
  const float* bihs; const float* bhhs;
  const float* Wp;
  float* out_h; float* pPart;
};

__global__ __launch_bounds__(512, 2) void k_scan(ScanArgs A) {
  cg::grid_group grid = cg::this_grid();
  const int w    = blockIdx.x;
  const int tid  = threadIdx.x;
  const int lane = tid & 63;
  const int ws   = tid >> 6;       // wave 0..7
  const int l16  = lane & 15;
  const int quad = lane >> 4;
  const int pj   = tid & 7;        // pointwise d-offset
  const int pb   = tid >> 3;       // pointwise batch
  const bool isL = (w < NWG_L);

  __shared__ float par[8][32][68];   // [wave][row32][batch64+pad]
  __shared__ float pbuf[64][17];

  // ---- weight fragment preload (register-resident for all 512 steps) ----
  // row map: n_local = nt*16+l16 -> gate g = n_local>>3, d-offset j = n_local&7
  // K stripe: k = ws*32 + kt*256 + quad*8
  bf16x8 bwh[2][6], bwl[2][6];
  if (isL) {
#pragma unroll
    for (int nt = 0; nt < 2; ++nt) {
      int nl = nt * 16 + l16;
      int g = nl >> 3, j = nl & 7;
      const size_t roff = (size_t)(g * HL_ + 8 * w + j) * KL_;
#pragma unroll
      for (int kt = 0; kt < 6; ++kt) {
        int k = ws * 32 + kt * 256 + quad * 8;
        bwh[nt][kt] = *reinterpret_cast<const bf16x8*>(A.Wl_hi + roff + k);
        bwl[nt][kt] = *reinterpret_cast<const bf16x8*>(A.Wl_lo + roff + k);
      }
    }
  } else {
    int w2 = w - NWG_L;
#pragma unroll
    for (int nt = 0; nt < 2; ++nt) {
      int nl = nt * 16 + l16;
      int g = nl >> 3, j = nl & 7;
      const size_t roff = (size_t)(g * HS_ + 8 * w2 + j) * KS_;
#pragma unroll
      for (int kt = 0; kt < 3; ++kt) {
        int k = ws * 32 + kt * 256 + quad * 8;
        bwh[nt][kt] = *reinterpret_cast<const bf16x8*>(A.Ws_hi + roff + k);
        bwl[nt][kt] = *reinterpret_cast<const bf16x8*>(A.Ws_lo + roff + k);
      }
    }
  }

  // per-thread recurrent state (c and prev blended h)
  float c_st = 0.f, h_st = 0.f;

  // per-thread constants
  float b4[4];
  float wph0 = 0.f, wpc0 = 0.f, wph1 = 0.f, wpc1 = 0.f;
  int d;
  if (isL) {
    d = 8 * w + pj;
#pragma unroll
    for (int g = 0; g < 4; ++g) b4[g] = A.bihl[g * HL_ + d] + A.bhhl[g * HL_ + d];
    wph0 = A.Wp[E_ + d];        wpc0 = A.Wp[E_ + HL_ + d];
    wph1 = A.Wp[2560 + E_ + d]; wpc1 = A.Wp[2560 + E_ + HL_ + d];
  } else {
    d = 8 * (w - NWG_L) + pj;
#pragma unroll
    for (int g = 0; g < 4; ++g) b4[g] = A.bihs[g * HS_ + d] + A.bhhs[g * HS_ + d];
  }

  // it = -1 : small-cell prologue (computes hs[0]); large idles.
  // it >= 0 : large does step t=it; small does step t=it+1 (one ahead).
#pragma unroll 1
  for (int it = -1; it < L_; ++it) {
    if (isL) {
      if (it >= 0) {
        const int t = it;
        f32x4 acc[4][2];
#pragma unroll
        for (int mt = 0; mt < 4; ++mt)
#pragma unroll
          for (int nt = 0; nt < 2; ++nt) {
            acc[mt][nt][0] = 0.f; acc[mt][nt][1] = 0.f;
            acc[mt][nt][2] = 0.f; acc[mt][nt][3] = 0.f;
          }
        const uint16_t* eh = A.Ahi + (size_t)t * (B_ * E_);
        const uint16_t* hh = A.h_hi + ((t - 1) & 1) * (B_ * HL_);
        const uint16_t* hl = A.h_lo + ((t - 1) & 1) * (B_ * HL_);
        // E-part (kt 0..1): 2-term (emb lo negligible)
#pragma unroll
        for (int kt = 0; kt < 2; ++kt) {
          const int koff = ws * 32 + kt * 256 + quad * 8;
          bf16x8 ah[4];
#pragma unroll
          for (int mt = 0; mt < 4; ++mt)
            ah[mt] = *reinterpret_cast<const bf16x8*>(eh + (mt * 16 + l16) * E_ + koff);
#pragma unroll
          for (int mt = 0; mt < 4; ++mt)
#pragma unroll
            for (int nt = 0; nt < 2; ++nt) {
              acc[mt][nt] = __builtin_amdgcn_mfma_f32_16x16x32_bf16(ah[mt], bwh[nt][kt], acc[mt][nt], 0, 0, 0);
              acc[mt][nt] = __builtin_amdgcn_mfma_f32_16x16x32_bf16(ah[mt], bwl[nt][kt], acc[mt][nt], 0, 0, 0);
            }
        }
        // H-part (kt 2..5): 3-term split precision
#pragma unroll
        for (int kt = 2; kt < 6; ++kt) {
          const int koff = ws * 32 + (kt - 2) * 256 + quad * 8;
          bf16x8 ah[4], al[4];
#pragma unroll
          for (int mt = 0; mt < 4; ++mt) {
            ah[mt] = *reinterpret_cast<const bf16x8*>(hh + (mt * 16 + l16) * HL_ + koff);
            al[mt] = *reinterpret_cast<const bf16x8*>(hl + (mt * 16 + l16) * HL_ + koff);
          }
#pragma unroll
          for (int mt = 0; mt < 4; ++mt)
#pragma unroll
            for (int nt = 0; nt < 2; ++nt) {
              acc[mt][nt] = __builtin_amdgcn_mfma_f32_16x16x32_bf16(ah[mt], bwh[nt][kt], acc[mt][nt], 0, 0, 0);
              acc[mt][nt] = __builtin_amdgcn_mfma_f32_16x16x32_bf16(al[mt], bwh[nt][kt], acc[mt][nt], 0, 0, 0);
              acc[mt][nt] = __builtin_amdgcn_mfma_f32_16x16x32_bf16(ah[mt], bwl[nt][kt], acc[mt][nt], 0, 0, 0);
            }
        }
        // partials -> LDS  (D layout: batch m = mt*16+quad*4+reg, row n = nt*16+l16)
#pragma unroll
        for (int mt = 0; mt < 4; ++mt)
#pragma unroll
          for (int nt = 0; nt < 2; ++nt)
            *reinterpret_cast<f32x4*>(&par[ws][nt * 16 + l16][mt * 16 + quad * 4]) = acc[mt][nt];
        __syncthreads();
        // reduce + pointwise: thread <-> (pb, d=8w+pj)
        float g4[4];
#pragma unroll
        for (int g = 0; g < 4; ++g) {
          float v = b4[g];
#pragma unroll
          for (int s = 0; s < 8; ++s) v += par[s][g * 8 + pj][pb];
          g4[g] = v;
        }
        float cn = sigm(g4[1]) * c_st + sigm(g4[0]) * tanhf(g4[2]);
        float hn = sigm(g4[3]) * tanhf(cn);
        float r0 = A.rseq[(t * B_ + pb) * 2 + 0];
        float r1 = A.rseq[(t * B_ + pb) * 2 + 1];
        float hb, cb2;
        if (d < HS_) {  // WG-uniform: w < 32
          hb  = A.hs_f32[(t & 1) * (B_ * HS_) + pb * HS_ + d];
          cb2 = A.cs_f32[(t & 1) * (B_ * HS_) + pb * HS_ + d];
        } else {
          hb = h_st; cb2 = cn;
        }
        float hnext = r0 * hn + r1 * hb;
        float cnext = r0 * cn + r1 * cb2;
        c_st = cnext; h_st = hnext;
        uint16_t hhi16 = f2bf(hnext);
        A.h_hi[(t & 1) * (B_ * HL_) + pb * HL_ + d] = hhi16;
        A.h_lo[(t & 1) * (B_ * HL_) + pb * HL_ + d] = f2bf(hnext - bf2f(hhi16));
        A.out_h[((size_t)pb * L_ + t) * HL_ + d] = hnext;
        // p partial (uses UNblended hn, cn)
        pbuf[pb][pj * 2 + 0] = hn * wph0 + cn * wpc0;
        pbuf[pb][pj * 2 + 1] = hn * wph1 + cn * wpc1;
        __syncthreads();
        if (tid < 128) {
          int b = tid >> 1, c = tid & 1;
          float s = 0.f;
#pragma unroll
          for (int j = 0; j < 8; ++j) s += pbuf[b][j * 2 + c];
          A.pPart[(((size_t)t * NWG_L + w) * B_ + b) * 2 + c] = s;
        }
      }
    } else {
      const int ts = it + 1;
      if (ts < L_) {
        f32x4 acc[4][2];
#pragma unroll
        for (int mt = 0; mt < 4; ++mt)
#pragma unroll
          for (int nt = 0; nt < 2; ++nt) {
            acc[mt][nt][0] = 0.f; acc[mt][nt][1] = 0.f;
            acc[mt][nt][2] = 0.f; acc[mt][nt][3] = 0.f;
          }
        const uint16_t* eh = A.Ahi + (size_t)ts * (B_ * E_);
        const uint16_t* hh = A.hs_hi + ((ts - 1) & 1) * (B_ * HS_);
        const uint16_t* hl = A.hs_lo + ((ts - 1) & 1) * (B_ * HS_);
#pragma unroll
        for (int kt = 0; kt < 2; ++kt) {
          const int koff = ws * 32 + kt * 256 + quad * 8;
          bf16x8 ah[4];
#pragma unroll
          for (int mt = 0; mt < 4; ++mt)
            ah[mt] = *reinterpret_cast<const bf16x8*>(eh + (mt * 16 + l16) * E_ + koff);
#pragma unroll
          for (int mt = 0; mt < 4; ++mt)
#pragma unroll
            for (int nt = 0; nt < 2; ++nt) {
              acc[mt][nt] = __builtin_amdgcn_mfma_f32_16x16x32_bf16(ah[mt], bwh[nt][kt], acc[mt][nt], 0, 0, 0);
              acc[mt][nt] = __builtin_amdgcn_mfma_f32_16x16x32_bf16(ah[mt], bwl[nt][kt], acc[mt][nt], 0, 0, 0);
            }
        }
        {  // hs-part (kt = 2): 3-term
          const int koff = ws * 32 + quad * 8;
          bf16x8 ah[4], al[4];
#pragma unroll
          for (int mt = 0; mt < 4; ++mt) {
            ah[mt] = *reinterpret_cast<const bf16x8*>(hh + (mt * 16 + l16) * HS_ + koff);
            al[mt] = *reinterpret_cast<const bf16x8*>(hl + (mt * 16 + l16) * HS_ + koff);
          }
#pragma unroll
          for (int mt = 0; mt < 4; ++mt)
#pragma unroll
            for (int nt = 0; nt < 2; ++nt) {
              acc[mt][nt] = __builtin_amdgcn_mfma_f32_16x16x32_bf16(ah[mt], bwh[nt][2], acc[mt][nt], 0, 0, 0);
              acc[mt][nt] = __builtin_amdgcn_mfma_f32_16x16x32_bf16(al[mt], bwh[nt][2], acc[mt][nt], 0, 0, 0);
              acc[mt][nt] = __builtin_amdgcn_mfma_f32_16x16x32_bf16(ah[mt], bwl[nt][2], acc[mt][nt], 0, 0, 0);
            }
        }
#pragma unroll
        for (int mt = 0; mt < 4; ++mt)
#pragma unroll
          for (int nt = 0; nt < 2; ++nt)
            *reinterpret_cast<f32x4*>(&par[ws][nt * 16 + l16][mt * 16 + quad * 4]) = acc[mt][nt];
        __syncthreads();
        float g4[4];
#pragma unroll
        for (int g = 0; g < 4; ++g) {
          float v = b4[g];
#pragma unroll
          for (int s = 0; s < 8; ++s) v += par[s][g * 8 + pj][pb];
          g4[g] = v;
        }
        float csn = sigm(g4[1]) * c_st + sigm(g4[0]) * tanhf(g4[2]);
        float hsn = sigm(g4[3]) * tanhf(csn);
        c_st = csn;
        int o = (ts & 1) * (B_ * HS_) + pb * HS_ + d;
        uint16_t hh16 = f2bf(hsn);
        A.hs_hi[o] = hh16;
        A.hs_lo[o] = f2bf(hsn - bf2f(hh16));
        A.hs_f32[o] = hsn;
        A.cs_f32[o] = csn;
        __syncthreads();  // protect par before next iteration's overwrite
      }
    }
    grid.sync();
  }
}

// ---------------- final kernels ----------------

__global__ __launch_bounds__(256) void k_cls1(
    const float* __restrict__ out_h, const float* __restrict__ Wc1,
    const float* __restrict__ bc1, float* __restrict__ z1) {
  int idx = blockIdx.x * 256 + threadIdx.x;  // < 64*512
  int b = idx >> 9, j = idx & 511;
  float s = bc1[j];
  const float* hr = out_h + (size_t)b * L_ * HL_ + (size_t)(L_ - 1) * HL_;
  const float* wr = Wc1 + (size_t)j * HL_;
  for (int dd = 0; dd < HL_; ++dd) s += fmaxf(hr[dd], 0.f) * wr[dd];
  z1[idx] = fmaxf(s, 0.f);
}

__global__ __launch_bounds__(64) void k_cls2(
    const float* __restrict__ z1, const float* __restrict__ Wc2,
    const float* __restrict__ bc2, float* __restrict__ out) {
  int b = blockIdx.x;
  int tid = threadIdx.x;
  __shared__ float sv[NC_];
  if (tid < NC_) {
    float s = bc2[tid];
    const float* zr = z1 + b * 512;
    const float* wr = Wc2 + tid * 512;
    for (int k = 0; k < 512; ++k) s += zr[k] * wr[k];
    sv[tid] = s;
  }
  __syncthreads();
  if (tid == 0) {
    float m = sv[0];
    for (int j = 1; j < NC_; ++j) m = fmaxf(m, sv[j]);
    float e[NC_], sum = 0.f;
    for (int j = 0; j < NC_; ++j) { e[j] = expf(sv[j] - m); sum += e[j]; }
    float inv = 1.0f / sum;
    for (int j = 0; j < NC_; ++j) out[b * NC_ + j] = e[j] * inv;
  }
}

__global__ __launch_bounds__(256) void k_pfinal(
    const float* __restrict__ pPart, const float* __restrict__ Pe,
    const float* __restrict__ bp, float* __restrict__ out_p) {
  int idx = blockIdx.x * 256 + threadIdx.x;  // b*512+t
  int b = idx >> 9, t = idx & 511;
  float s0 = Pe[(t * B_ + b) * 2 + 0] + bp[0];
  float s1 = Pe[(t * B_ + b) * 2 + 1] + bp[1];
  for (int w = 0; w < NWG_L; ++w) {
    const float* p = pPart + (((size_t)t * NWG_L + w) * B_ + b) * 2;
    s0 += p[0];
    s1 += p[1];
  }
  float m = fmaxf(s0, s1);
  float e0 = expf(s0 - m), e1 = expf(s1 - m);
  float inv = 1.0f / (e0 + e1);
  out_p[(size_t)idx * 2 + 0] = e0 * inv;
  out_p[(size_t)idx * 2 + 1] = e1 * inv;
}

// ---------------- host ----------------
extern "C" void kernel_launch(void* const* d_in, const int* in_sizes, int n_in,
                              void* d_out, int out_size, void* d_ws, size_t ws_size,
                              hipStream_t stream) {
  const int*   x    = (const int*)d_in[0];
  const float* gum  = (const float*)d_in[1];
  const float* emb  = (const float*)d_in[2];
  const float* Wihl = (const float*)d_in[3];
  const float* Whhl = (const float*)d_in[4];
  const float* bihl = (const float*)d_in[5];
  const float* bhhl = (const float*)d_in[6];
  const float* Wihs = (const float*)d_in[7];
  const float* Whhs = (const float*)d_in[8];
  const float* bihs = (const float*)d_in[9];
  const float* bhhs = (const float*)d_in[10];
  const float* Wp   = (const float*)d_in[11];
  const float* bp   = (const float*)d_in[12];
  const float* Wc1  = (const float*)d_in[13];
  const float* bc1  = (const float*)d_in[14];
  const float* Wc2  = (const float*)d_in[15];
  const float* bc2  = (const float*)d_in[16];
  float* out = (float*)d_out;

  char* ws = (char*)d_ws;
  // workspace layout (bytes) — ~97 MB
  uint16_t* Ahi   = (uint16_t*)(ws + 0);           // 33,554,432  [L][B][E]
  uint16_t* Wl_hi = (uint16_t*)(ws + 33554432);    // 12,582,912
  uint16_t* Wl_lo = (uint16_t*)(ws + 46137344);    // 12,582,912
  uint16_t* Ws_hi = (uint16_t*)(ws + 58720256);    //  1,572,864
  uint16_t* Ws_lo = (uint16_t*)(ws + 60293120);    //  1,572,864
  float*    pPart = (float*)   (ws + 61865984);    // 33,554,432  [L][128][64][2]
  uint16_t* h_hi  = (uint16_t*)(ws + 95420416);    //    262,144  [2][64][1024]
  uint16_t* h_lo  = (uint16_t*)(ws + 95682560);    //    262,144
  uint16_t* hs_hi = (uint16_t*)(ws + 95944704);    //     65,536  [2][64][256]
  uint16_t* hs_lo = (uint16_t*)(ws + 96010240);    //     65,536
  float*    hs_f  = (float*)   (ws + 96075776);    //    131,072  [2][64][256]
  float*    cs_f  = (float*)   (ws + 96206848);    //    131,072
  float*    rseq  = (float*)   (ws + 96337920);    //    262,144  [L][B][2]
  float*    Pe    = (float*)   (ws + 96600064);    //    262,144  [L][B][2]
  float*    z1    = (float*)   (ws + 96862208);    //    131,072  [64][512]

  float* out_logits = out;
  float* out_h      = out + 320;
  float* out_p      = out + 320 + (size_t)B_ * L_ * HL_;

  // ---- setup ----
  {
    int n = 4096 * KL_ + 1024 * KS_;
    k_convw<<<(n + 255) / 256, 256, 0, stream>>>(Wihl, Whhl, Wihs, Whhs,
                                                 Wl_hi, Wl_lo, Ws_hi, Ws_lo);
  }
  k_embed<<<(L_ * B_ * E_) / 256, 256, 0, stream>>>(x, emb, Ahi);
  {
    int nwords = (96337920 - 95420416) / 4;  // h_hi..cs_f region
    k_zero<<<(nwords + 255) / 256, 256, 0, stream>>>((uint32_t*)(ws + 95420416), nwords);
  }
  k_rseq<<<(L_ * B_) / 256, 256, 0, stream>>>(gum, rseq);
  k_pe<<<(L_ * B_) / 256, 256, 0, stream>>>(x, emb, Wp, Pe);

  // ---- persistent cooperative scan ----
  ScanArgs sa;
  sa.Ahi = Ahi; sa.Wl_hi = Wl_hi; sa.Wl_lo = Wl_lo; sa.Ws_hi = Ws_hi; sa.Ws_lo = Ws_lo;
  sa.h_hi = h_hi; sa.h_lo = h_lo; sa.hs_hi = hs_hi; sa.hs_lo = hs_lo;
  sa.hs_f32 = hs_f; sa.cs_f32 = cs_f;
  sa.rseq = rseq; sa.bihl = bihl; sa.bhhl = bhhl; sa.bihs = bihs; sa.bhhs = bhhs;
  sa.Wp = Wp; sa.out_h = out_h; sa.pPart = pPart;
  void* args[] = { &sa };
  hipLaunchCooperativeKernel((const void*)k_scan, dim3(NWG_), dim3(512), args, 0, stream);

  // ---- epilogue ----
  k_cls1<<<(B_ * 512) / 256, 256, 0, stream>>>(out_h, Wc1, bc1, z1);
  k_cls2<<<B_, 64, 0, stream>>>(z1, Wc2, bc2, out_logits);
  k_pfinal<<<(B_ * L_) / 256, 256, 0, stream>>>(pPart, Pe, bp, out_p);
}